// Round 21
// baseline (251.002 us; speedup 1.0000x reference)
//
#include <hip/hip_runtime.h>
#include <hip/hip_bf16.h>
#include <cstddef>
#include <cmath>
#include <algorithm>

#define SEQ 2048
#define DMODEL 256
#define NHEAD 4
#define DK 64
#define VDIM 512
#define DV 128
#define NB 2
#define FDIM 1024
#define NROWS (NB*SEQ)   // 4096
#define QKVGN 1536       // 256 q + 256 k + 512 v + 512 g
#define NSLOT 144        // q64-tiles: sum over qt64 of ((qt64>>2)+1)

typedef unsigned short u16;
typedef __attribute__((ext_vector_type(8))) short short8;
typedef __attribute__((ext_vector_type(4))) short short4v;
typedef __attribute__((ext_vector_type(4))) float f32x4;

static __device__ __forceinline__ u16 f2b(float f) {
    union { float f; unsigned u; } c; c.f = f;
    unsigned r = c.u + 0x7fffu + ((c.u >> 16) & 1u);
    return (u16)(r >> 16);
}
static __device__ __forceinline__ float b2f(u16 u) {
    union { unsigned u; float f; } c; c.u = ((unsigned)u) << 16; return c.f;
}

static __device__ __forceinline__ short4v pack_bf16x4(float a0, float a1, float a2, float a3) {
    union { short4v v; unsigned u[2]; } z;
    union { __hip_bfloat162 h; unsigned u; } p0, p1;
    p0.h = __float22bfloat162_rn(make_float2(a0, a1));
    p1.h = __float22bfloat162_rn(make_float2(a2, a3));
    z.u[0] = p0.u; z.u[1] = p1.u;
    return z.v;
}

static __device__ __forceinline__ short8 pack_bf16x8(float a0, float a1, float a2, float a3,
                                                     float c0, float c1, float c2, float c3) {
    union { short8 v; unsigned u[4]; } z;
    union { __hip_bfloat162 h; unsigned u; } p;
    p.h = __float22bfloat162_rn(make_float2(a0, a1)); z.u[0] = p.u;
    p.h = __float22bfloat162_rn(make_float2(a2, a3)); z.u[1] = p.u;
    p.h = __float22bfloat162_rn(make_float2(c0, c1)); z.u[2] = p.u;
    p.h = __float22bfloat162_rn(make_float2(c2, c3)); z.u[3] = p.u;
    return z.v;
}

// async global -> LDS, 16B per lane (wave-uniform LDS base + lane*16)
#define GLOAD_LDS16(GP, LP) \
    __builtin_amdgcn_global_load_lds((const __attribute__((address_space(1))) void*)(GP), \
                                     (__attribute__((address_space(3))) void*)(LP), 16, 0, 0)

// ---------------- merged setup: sin/cos tables + all 7 weight transposes + layer-0 LN ----------------
// grid 4608 x 256: blocks 0..511 = tables; 512..3583 = wconv; 3584..4607 = LN of x0.
__global__ __launch_bounds__(256) void setup_kernel(
    const float* __restrict__ Wq, const float* __restrict__ Wk,
    const float* __restrict__ Wv, const float* __restrict__ Wg,
    const float* __restrict__ Wo, const float* __restrict__ W1,
    const float* __restrict__ W2,
    u16* __restrict__ wqkvg_t, u16* __restrict__ wo_t,
    u16* __restrict__ w1_t, u16* __restrict__ w2_t,
    float* __restrict__ sint, float* __restrict__ cost,
    const float* __restrict__ x0, const float* __restrict__ ln1w,
    const float* __restrict__ ln1b, u16* __restrict__ xln)
{
    __shared__ float tile[32][33];
    int bid = blockIdx.x;
    if (bid < 512) {                       // sin/cos tables: SEQ*DK = 131072 elems
        int idx = bid * 256 + threadIdx.x;
        int s = idx >> 6, d = idx & 63;
        int j = d >> 1;
        float a = powf(10000.f, -(float)j / 31.f);
        float arg = (float)s * a;
        sint[idx] = sinf(arg);
        cost[idx] = cosf(arg);
        return;
    }
    if (bid >= 3584) {                     // layer-0 LN: wave-per-row
        int row = (bid - 3584) * 4 + (threadIdx.x >> 6);
        int lane = threadIdx.x & 63;
        size_t base = (size_t)row * DMODEL + lane * 4;
        f32x4 v = *(const f32x4*)(x0 + base);
        float s  = v[0] + v[1] + v[2] + v[3];
        float s2 = v[0]*v[0] + v[1]*v[1] + v[2]*v[2] + v[3]*v[3];
        #pragma unroll
        for (int st = 1; st < 64; st <<= 1) { s += __shfl_xor(s, st); s2 += __shfl_xor(s2, st); }
        float mu = s * (1.f / 256.f);
        float var = s2 * (1.f / 256.f) - mu * mu;
        float rstd = rsqrtf(var + 1e-5f);
        f32x4 wv = *(const f32x4*)(ln1w + lane * 4);
        f32x4 bv = *(const f32x4*)(ln1b + lane * 4);
        f32x4 r = (v - mu) * rstd * wv + bv;
        *(short4v*)(xln + base) = pack_bf16x4(r[0], r[1], r[2], r[3]);
        return;
    }
    bid -= 512;
    const float* in; u16* out; int K, N, nx, ny;
    size_t in_ls, out_ls;
    const size_t WLQ = (size_t)QKVGN * DMODEL;
    if (bid < 192)       {            in = Wq; out = wqkvg_t;              K = 256;  N = 256;  nx = 8;  ny = 8;  in_ls = 256*256;          out_ls = WLQ; }
    else if (bid < 384)  { bid -= 192;  in = Wk; out = wqkvg_t + 256*256;  K = 256;  N = 256;  nx = 8;  ny = 8;  in_ls = 256*256;          out_ls = WLQ; }
    else if (bid < 768)  { bid -= 384;  in = Wv; out = wqkvg_t + 512*256;  K = 256;  N = 512;  nx = 16; ny = 8;  in_ls = (size_t)256*512;  out_ls = WLQ; }
    else if (bid < 1152) { bid -= 768;  in = Wg; out = wqkvg_t + 1024*256; K = 256;  N = 512;  nx = 16; ny = 8;  in_ls = (size_t)256*512;  out_ls = WLQ; }
    else if (bid < 1536) { bid -= 1152; in = Wo; out = wo_t;               K = 512;  N = 256;  nx = 8;  ny = 16; in_ls = (size_t)512*256;  out_ls = (size_t)512*256; }
    else if (bid < 2304) { bid -= 1536; in = W1; out = w1_t;               K = 256;  N = 1024; nx = 32; ny = 8;  in_ls = (size_t)256*1024; out_ls = (size_t)256*1024; }
    else                 { bid -= 2304; in = W2; out = w2_t;               K = 1024; N = 256;  nx = 8;  ny = 32; in_ls = (size_t)1024*256; out_ls = (size_t)1024*256; }
    int per = nx * ny;
    int z = bid / per, rem = bid % per;
    int by = rem / nx, bx = rem % nx;
    int tx = threadIdx.x & 31, ty = threadIdx.x >> 5;
    const float* inz = in + (size_t)z * in_ls;
    u16* outz = out + (size_t)z * out_ls;
    int n0 = bx * 32, k0 = by * 32;
    #pragma unroll
    for (int r = 0; r < 4; ++r) {
        int kr = ty + r * 8;
        tile[kr][tx] = inz[(size_t)(k0 + kr) * N + n0 + tx];
    }
    __syncthreads();
    #pragma unroll
    for (int r = 0; r < 4; ++r) {
        int nr = ty + r * 8;
        outz[(size_t)(n0 + nr) * K + k0 + tx] = f2b(tile[tx][nr]);
    }
}

// -------- combine NPART bf16 split-K partials (+opt bias) + residual -> yout, then LN -> bf16 --------
template<int NPART, int HASBIAS>
__global__ __launch_bounds__(256) void lncomb_kernel(const u16* __restrict__ pW,
                                                     const float* __restrict__ bias,
                                                     const float* __restrict__ res,
                                                     const float* __restrict__ w,
                                                     const float* __restrict__ b,
                                                     float* __restrict__ yout,
                                                     u16* __restrict__ o)
{
    int row = blockIdx.x * 4 + (threadIdx.x >> 6);
    int lane = threadIdx.x & 63;
    size_t base = (size_t)row * DMODEL + lane * 4;
    const size_t PS = (size_t)NROWS * DMODEL;
    f32x4 v = *(const f32x4*)(res + base);
    #pragma unroll
    for (int k = 0; k < NPART; ++k) {
        short4v sv = *(const short4v*)(pW + base + k * PS);
        v[0] += b2f((u16)sv[0]); v[1] += b2f((u16)sv[1]);
        v[2] += b2f((u16)sv[2]); v[3] += b2f((u16)sv[3]);
    }
    if (HASBIAS) v += *(const f32x4*)(bias + lane * 4);
    *(f32x4*)(yout + base) = v;
    float s  = v[0] + v[1] + v[2] + v[3];
    float s2 = v[0]*v[0] + v[1]*v[1] + v[2]*v[2] + v[3]*v[3];
    #pragma unroll
    for (int st = 1; st < 64; st <<= 1) { s += __shfl_xor(s, st); s2 += __shfl_xor(s2, st); }
    float mu = s * (1.f / 256.f);
    float var = s2 * (1.f / 256.f) - mu * mu;
    float rstd = rsqrtf(var + 1e-5f);
    f32x4 wv = *(const f32x4*)(w + lane * 4);
    f32x4 bv = *(const f32x4*)(b + lane * 4);
    f32x4 r = (v - mu) * rstd * wv + bv;
    *(short4v*)(o + base) = pack_bf16x4(r[0], r[1], r[2], r[3]);
}

// ---- final: combine 4 bf16 W2 partials + bias + residual -> d_out (fp32), wave-per-row ----
__global__ __launch_bounds__(256) void comb4_kernel(const u16* __restrict__ pW,
                                                    const float* __restrict__ bias,
                                                    const float* __restrict__ yb,
                                                    float* __restrict__ out)
{
    int row = blockIdx.x * 4 + (threadIdx.x >> 6);
    int lane = threadIdx.x & 63;
    size_t base = (size_t)row * DMODEL + lane * 4;
    const size_t PS = (size_t)NROWS * DMODEL;
    f32x4 v = *(const f32x4*)(yb + base);
    v += *(const f32x4*)(bias + lane * 4);
    #pragma unroll
    for (int k = 0; k < 4; ++k) {
        short4v sv = *(const short4v*)(pW + base + k * PS);
        v[0] += b2f((u16)sv[0]); v[1] += b2f((u16)sv[1]);
        v[2] += b2f((u16)sv[2]); v[3] += b2f((u16)sv[3]);
    }
    *(f32x4*)(out + base) = v;
}

// ------------- 64xBNW bf16 MFMA GEMM, BK=64, gload_lds staging -------------
// 4 waves (2x2): wave tile 32 x (BNW/2). BNW=64: acc[2][2] (round-12 proven byte-identical);
// BNW=128: acc[2][4], reads:MFMA ratio 0.75 (LDS-issue relief), barriers halved per FLOP.
// Both-sides XOR swizzle (8-col8). VT: v-cols (512..1023) -> transposed interleaved vt.
template<int BIAS, int GELU, int ROT, int OUTBF, int SPLIT, int VT, int BNW>
__global__ __launch_bounds__(256) void gemm64(const u16* __restrict__ A,
                                              const u16* __restrict__ Bt,
                                              void* __restrict__ Cout,
                                              const float* __restrict__ bias,
                                              const float* __restrict__ sint,
                                              const float* __restrict__ cost,
                                              u16* __restrict__ vtout,
                                              int M, int N, int K, int kslice)
{
    constexpr int NI = BNW / 32;       // col frags per wave
    constexpr int NBL = BNW / 32;      // B gload chunks per thread
    __shared__ __align__(16) u16 As[64 * 64];
    __shared__ __align__(16) u16 Bs[BNW * 64];
    int bx = blockIdx.x, by = blockIdx.y;
    int tid = threadIdx.x;
    int wave = tid >> 6, lane = tid & 63;
    int wm = wave & 1, wn = wave >> 1;
    int l15 = lane & 15, lg = lane >> 4;
    int kb0 = SPLIT ? blockIdx.z * kslice : 0;
    int kcnt = SPLIT ? kslice : K;

    int L0 = tid;
    int r0 = L0 >> 3, c0g = (L0 & 7) ^ ((r0 >> 1) & 7);
    int L1 = 256 + tid;
    int r1 = L1 >> 3, c1g = (L1 & 7) ^ ((r1 >> 1) & 7);
    const u16* Ag0 = A + (size_t)(by * 64 + r0) * K + kb0 + c0g * 8;
    const u16* Ag1 = A + (size_t)(by * 64 + r1) * K + kb0 + c1g * 8;
    const u16* Bg[NBL];
    #pragma unroll
    for (int i = 0; i < NBL; ++i) {
        int L = i * 256 + tid;
        int r = L >> 3, cg = (L & 7) ^ ((r >> 1) & 7);
        Bg[i] = Bt + (size_t)(bx * BNW + r) * K + kb0 + cg * 8;
    }
    u16* Asw0 = &As[wave * 512];
    u16* Asw1 = &As[2048 + wave * 512];

    f32x4 acc[2][NI] = {};
    for (int k0 = 0; k0 < kcnt; k0 += 64) {
        GLOAD_LDS16(Ag0 + k0, Asw0);
        GLOAD_LDS16(Ag1 + k0, Asw1);
        #pragma unroll
        for (int i = 0; i < NBL; ++i)
            GLOAD_LDS16(Bg[i] + k0, &Bs[i * 2048 + wave * 512]);
        __syncthreads();               // drains vmcnt -> staged data visible
        #pragma unroll
        for (int kk = 0; kk < 2; ++kk) {
            short8 af[2], bf[NI];
            #pragma unroll
            for (int i = 0; i < 2; ++i) {
                int ra = wm * 32 + i * 16 + l15;
                af[i] = *(const short8*)&As[ra * 64 + ((kk * 4 + lg) ^ ((ra >> 1) & 7)) * 8];
            }
            #pragma unroll
            for (int ni = 0; ni < NI; ++ni) {
                int rb = wn * (BNW / 2) + ni * 16 + l15;
                bf[ni] = *(const short8*)&Bs[rb * 64 + ((kk * 4 + lg) ^ ((rb >> 1) & 7)) * 8];
            }
            #pragma unroll
            for (int mi = 0; mi < 2; ++mi)
                #pragma unroll
                for (int ni = 0; ni < NI; ++ni)
                    acc[mi][ni] = __builtin_amdgcn_mfma_f32_16x16x32_bf16(af[mi], bf[ni], acc[mi][ni], 0, 0, 0);
        }
        __syncthreads();               // protect LDS reuse
    }

    float* Cf = (float*)Cout;
    u16* Ch = (u16*)Cout;
    u16* Chs = (u16*)Cout;   // bf16 split partials
    #pragma unroll
    for (int mi = 0; mi < 2; ++mi)
        #pragma unroll
        for (int ni = 0; ni < NI; ++ni) {
            int colb = bx * BNW + wn * (BNW / 2) + ni * 16;   // wave-uniform base of this 16-col group
            if (VT && colb >= 512 && colb < 1024) {
                int col = colb + l15;
                int z = ((by >> 5) << 2) + ((col - 512) >> 7);   // b*4 + h
                int dv = (col - 512) & 127;
                int s0b = (by * 64 + wm * 32) & (SEQ - 1);
                short4v pk = pack_bf16x4(acc[mi][ni][0], acc[mi][ni][1], acc[mi][ni][2], acc[mi][ni][3]);
                *(short4v*)(vtout + (size_t)(z * DV + dv) * SEQ + s0b + lg * 8 + mi * 4) = pk;
            } else {
                #pragma unroll
                for (int r = 0; r < 4; ++r) {
                    int row = by * 64 + wm * 32 + mi * 16 + lg * 4 + r;
                    int col = colb + l15;
                    float v = acc[mi][ni][r];
                    if (ROT) {
                        float pv = __shfl_xor(v, 1);   // partner (col^1), group-uniform branch
                        if (col < 512) {
                            int s = row & (SEQ - 1);
                            int dk = col & 63;
                            float c = cost[(s << 6) + dk], sn = sint[(s << 6) + dk];
                            float rv = (col & 1) ? (v * c + pv * sn) : (v * c - pv * sn);
                            v = (col < 256) ? rv : rv * 0.125f;   // k gets DK^-0.5
                        }
                    }
                    if (BIAS) v += bias[col];
                    if (GELU) v = 0.5f * v * (1.f + erff(v * 0.70710678118654752f));
                    if (SPLIT)      Chs[(size_t)blockIdx.z * M * N + (size_t)row * N + col] = f2b(v);
                    else if (OUTBF) Ch[(size_t)row * N + col] = f2b(v);
                    else            Cf[(size_t)row * N + col] = v;
                }
            }
        }
}

// ---------------- retention pass 1 (swapped-QK, LDS-staged 2-phase, 64 q-rows/block) ----
// 1D grid 1152: bh = bid&7 (XCD pin), f = bid>>3 = slot decoding (qt64, chunk of 8 kv-tiles).
// 4 waves: wq in 0..3, each 16 q-rows x all 128 dv.
// PV uses full K=32 MFMA: the interleaved V layout (p = lg*8 + tt*4 + r <-> t = tt*16+lg*4+r)
// IS the 16x16x32 B-frag k-ordering when A is packed as [a0..a3, c0..c3].
__global__ __launch_bounds__(256) void retention_p1(
    const u16* __restrict__ qkvg, const u16* __restrict__ vt,
    u16* __restrict__ po, float* __restrict__ pden)
{
    __shared__ __align__(16) u16 Klds[2][2048];   // [8 seg][32 row][8 halves]
    __shared__ __align__(16) u16 Vlds[2][4096];   // [128 dv][32 halves interleaved]

    int bid = blockIdx.x;
    int bh = bid & 7;
    int f = bid >> 3;
    int a = 0, base = 0;
    while (f >= base + 4 * (a + 1)) { base += 4 * (a + 1); ++a; }   // tiers of 4 qt64s
    int segs = f - base;
    int qt64 = 4 * a + segs / (a + 1);
    int ch = segs % (a + 1);
    int b = bh >> 2, h = bh & 3;
    int slot = bh * NSLOT + f;

    int tid = threadIdx.x;
    int wave = tid >> 6, lane = tid & 63;
    int wq = wave;
    int l15 = lane & 15, lg = lane >> 4;

    float rgeo = 1.f - exp2f(-5.f - (float)h);
    float dec2 = log2f(rgeo);
    float step = exp2f(dec2 * -32.f);       // r^-32

    const u16* qbase  = qkvg + (size_t)b * SEQ * QKVGN + h * 64;
    const u16* kbase  = qbase + 256;
    const u16* vtg    = vt + (size_t)bh * DV * SEQ;

    int q0w = qt64 * 64 + wq * 16;
    short8 qf0 = *(const short8*)(qbase + (size_t)(q0w + l15) * QKVGN + lg * 8);
    short8 qf1 = *(const short8*)(qbase + (size_t)(q0w + l15) * QKVGN + 32 + lg * 8);

    int tb = ch * 8;                          // first kv-tile of this chunk
    int t_last = (ch == a) ? (2 * qt64 + 1) : (tb + 7);
    int hasdiag = (ch == a);

    float rinv  = exp2f(-dec2);               // r^-1
    float r16   = exp2f(dec2 * -16.f);        // r^-16
    float et00 = exp2f(dec2 * -(float)(tb * 32 + lg * 4));
    float et01 = et00 * rinv;
    float et02 = et01 * rinv;
    float et03 = et02 * rinv;
    float et10 = et00 * r16, et11 = et01 * r16, et12 = et02 * r16, et13 = et03 * r16;

    f32x4 oacc0 = {0.f,0.f,0.f,0.f}, oacc1 = {0.f,0.f,0.f,0.f};
    f32x4 oacc2 = {0.f,0.f,0.f,0.f}, oacc3 = {0.f,0.f,0.f,0.f};
    f32x4 oacc4 = {0.f,0.f,0.f,0.f}, oacc5 = {0.f,0.f,0.f,0.f};
    f32x4 oacc6 = {0.f,0.f,0.f,0.f}, oacc7 = {0.f,0.f,0.f,0.f};
    float den_l = 0.f;

#define STAGE(BUF, TI) do { \
    int t0_ = (TI) * 32; \
    _Pragma("unroll") \
    for (int ii = 0; ii < 3; ++ii) { \
        int inst_ = wave * 3 + ii; \
        if (inst_ < 4) { \
            const u16* g_ = kbase + (size_t)(t0_ + (lane & 31)) * QKVGN + (2 * inst_ + (lane >> 5)) * 8; \
            GLOAD_LDS16(g_, &Klds[BUF][inst_ * 512]); \
        } else { \
            int j_ = inst_ - 4; \
            const u16* g_ = vtg + (size_t)(j_ * 16 + (lane >> 2)) * SEQ + t0_ + (lane & 3) * 8; \
            GLOAD_LDS16(g_, &Vlds[BUF][j_ * 512]); \
        } \
    } \
} while (0)

#define BODY(BUF, T0, DIAG) do { \
    const u16* kb_ = &Klds[BUF][0]; \
    const u16* vb_ = &Vlds[BUF][0]; \
    short8 k00 = *(const short8*)(kb_ + (lg    ) * 256 + l15 * 8); \
    short8 k01 = *(const short8*)(kb_ + (4 + lg) * 256 + l15 * 8); \
    short8 k10 = *(const short8*)(kb_ + (lg    ) * 256 + (16 + l15) * 8); \
    short8 k11 = *(const short8*)(kb_ + (4 + lg) * 256 + (16 + l15) * 8); \
    short8 V0 = *(const short8*)(vb_ + (      l15) * 32 + lg * 8); \
    short8 V1 = *(const short8*)(vb_ + (16 +  l15) * 32 + lg * 8); \
    short8 V2 = *(const short8*)(vb_ + (32 +  l15) * 32 + lg * 8); \
    short8 V3 = *(const short8*)(vb_ + (48 +  l15) * 32 + lg * 8); \
    short8 V4 = *(const short8*)(vb_ + (64 +  l15) * 32 + lg * 8); \
    short8 V5 = *(const short8*)(vb_ + (80 +  l15) * 32 + lg * 8); \
    short8 V6 = *(const short8*)(vb_ + (96 +  l15) * 32 + lg * 8); \
    short8 V7 = *(const short8*)(vb_ + (112 + l15) * 32 + lg * 8); \
    f32x4 s0 = {0.f,0.f,0.f,0.f}, s1 = {0.f,0.f,0.f,0.f}; \
    s0 = __builtin_amdgcn_mfma_f32_16x16x32_bf16(k00, qf0, s0, 0, 0, 0); \
    s0 = __builtin_amdgcn_mfma_f32_16x16x32_bf16(k01, qf1, s0, 0, 0, 0); \
    s1 = __builtin_amdgcn_mfma_f32_16x16x32_bf16(k10, qf0, s1, 0, 0, 0); \
    s1 = __builtin_amdgcn_mfma_f32_16x16x32_bf16(k11, qf1, s1, 0, 0, 0); \
    float a0 = s0[0] * et00, a1 = s0[1] * et01, a2 = s0[2] * et02, a3 = s0[3] * et03; \
    float c0 = s1[0] * et10, c1 = s1[1] * et11, c2 = s1[2] * et12, c3 = s1[3] * et13; \
    if (DIAG) { \
        int qr_ = q0w + l15; \
        int tg_ = (T0) + lg * 4; \
        a0 = (tg_ +  0 <= qr_) ? a0 : 0.f;  a1 = (tg_ +  1 <= qr_) ? a1 : 0.f; \
        a2 = (tg_ +  2 <= qr_) ? a2 : 0.f;  a3 = (tg_ +  3 <= qr_) ? a3 : 0.f; \
        c0 = (tg_ + 16 <= qr_) ? c0 : 0.f;  c1 = (tg_ + 17 <= qr_) ? c1 : 0.f; \
        c2 = (tg_ + 18 <= qr_) ? c2 : 0.f;  c3 = (tg_ + 19 <= qr_) ? c3 : 0.f; \
    } \
    den_l += fabsf(a0) + fabsf(a1) + fabsf(a2) + fabsf(a3) \
           + fabsf(c0) + fabsf(c1) + fabsf(c2) + fabsf(c3); \
    short8 pa = pack_bf16x8(a0, a1, a2, a3, c0, c1, c2, c3); \
    oacc0 = __builtin_amdgcn_mfma_f32_16x16x32_bf16(pa, V0, oacc0, 0, 0, 0); \
    oacc1 = __builtin_amdgcn_mfma_f32_16x16x32_bf16(pa, V1, oacc1, 0, 0, 0); \
    oacc2 = __builtin_amdgcn_mfma_f32_16x16x32_bf16(pa, V2, oacc2, 0, 0, 0); \
    oacc3 = __builtin_amdgcn_mfma_f32_16x16x32_bf16(pa, V3, oacc3, 0, 0, 0); \
    oacc4 = __builtin_amdgcn_mfma_f32_16x16x32_bf16(pa, V4, oacc4, 0, 0, 0); \
    oacc5 = __builtin_amdgcn_mfma_f32_16x16x32_bf16(pa, V5, oacc5, 0, 0, 0); \
    oacc6 = __builtin_amdgcn_mfma_f32_16x16x32_bf16(pa, V6, oacc6, 0, 0, 0); \
    oacc7 = __builtin_amdgcn_mfma_f32_16x16x32_bf16(pa, V7, oacc7, 0, 0, 0); \
    et00 *= step; et01 *= step; et02 *= step; et03 *= step; \
    et10 *= step; et11 *= step; et12 *= step; et13 *= step; \
} while (0)

    int ti = tb;
    STAGE(0, tb);
    __syncthreads();
    for (; ti + 2 <= t_last; ti += 2) {
        STAGE(1, ti + 1);
        BODY(0, ti * 32, 0);
        __syncthreads();
        STAGE(0, ti + 2);
        BODY(1, (ti + 1) * 32, 0);
        __syncthreads();
    }
    if (ti < t_last) {          // two tiles remain (chunk lengths are always even)
        STAGE(1, ti + 1);
        BODY(0, ti * 32, hasdiag);     // with 64-row q-blocks the diagonal spans 2 tiles
        __syncthreads();
        BODY(1, (ti + 1) * 32, hasdiag);
    } else {                    // safety: single tile
        BODY(0, ti * 32, hasdiag);
    }
#undef STAGE
#undef BODY

    den_l += __shfl_xor(den_l, 16);
    den_l += __shfl_xor(den_l, 32);
    if (lane < 16)
        pden[(size_t)slot * 64 + wq * 16 + l15] = den_l;

    u16* pobase = po + (size_t)slot * (64 * 128) + (wq * 16 + lg * 4) * 128 + l15;
    #pragma unroll
    for (int r = 0; r < 4; ++r) {
        pobase[r * 128 +   0] = f2b(oacc0[r]);
        pobase[r * 128 +  16] = f2b(oacc1[r]);
        pobase[r * 128 +  32] = f2b(oacc2[r]);
        pobase[r * 128 +  48] = f2b(oacc3[r]);
        pobase[r * 128 +  64] = f2b(oacc4[r]);
        pobase[r * 128 +  80] = f2b(oacc5[r]);
        pobase[r * 128 +  96] = f2b(oacc6[r]);
        pobase[r * 128 + 112] = f2b(oacc7[r]);
    }
}

// ---------------- retention pass 2: reduce chunks, r^q scaling, clip, RMS, swish gate ----
// 1D grid 256: bh = bid&7, qt64 = bid>>3. 64 rows/block, 32 cols/thread.
__global__ __launch_bounds__(256) void retention_p2(
    const u16* __restrict__ po, const float* __restrict__ pden,
    const u16* __restrict__ qkvg, u16* __restrict__ og)
{
    int bid = blockIdx.x;
    int bh = bid & 7;
    int qt64 = bid >> 3;
    int b = bh >> 2, h = bh & 3;
    int aa = qt64 >> 2, rr = qt64 & 3;
    int sbase = bh * NSLOT + qt64 + 2 * aa * (aa - 1) + rr * aa;
    int nch = aa + 1;
    int t = threadIdx.x;
    int row = t >> 2, c0 = (t & 3) * 32;
    int q = qt64 * 64 + row;

    float den = 0.f;
    for (int k = 0; k < nch; ++k) den += pden[(size_t)(sbase + k) * 64 + row];
    float acc[32];
    #pragma unroll
    for (int j = 0; j < 32; ++j) acc[j] = 0.f;
    for (int k = 0; k < nch; ++k) {
        const u16* p = po + (size_t)(sbase + k) * (64 * 128) + row * 128 + c0;
        #pragma unroll
        for (int j = 0; j < 32; ++j) acc[j] += b2f(p[j]);
    }
    float rgeo = 1.f - exp2f(-5.f - (float)h);
    float dec2 = log2f(rgeo);
    float rp1 = exp2f(dec2 * (float)(q + 1));
    float cs = (1.f - rp1) / (1.f - rgeo);
    float invs = rsqrtf(cs);
    float eqv = exp2f(dec2 * (float)q);          // r^q (pass-1 deferred factor)
    float d = fmaxf(den * eqv * invs, 1.f);
    float scl = eqv * invs / d;
    float ss = 0.f;
    #pragma unroll
    for (int j = 0; j < 32; ++j) { float v = acc[j] * scl; acc[j] = v; ss += v * v; }
    ss += __shfl_xor(ss, 1); ss += __shfl_xor(ss, 2);
    float rms = rsqrtf(ss * (1.f / DV) + 1e-6f);

    const u16* gbase = qkvg + ((size_t)(b * SEQ + q)) * QKVGN + 1024 + h * DV + c0;
    u16* obase = og + ((size_t)(b * SEQ + q)) * VDIM + h * DV + c0;
    #pragma unroll
    for (int j = 0; j < 32; ++j) {
        float gv = b2f(gbase[j]);
        float sig = 1.f / (1.f + __expf(-gv));
        obase[j] = f2b(gv * sig * acc[j] * rms);
    }
}

extern "C" void kernel_launch(void* const* d_in, const int* in_sizes, int n_in,
                              void* d_out, int out_size, void* d_ws, size_t ws_size,
                              hipStream_t stream)
{
    const float* x0    = (const float*)d_in[0];
    const float* Wq    = (const float*)d_in[1];
    const float* Wk    = (const float*)d_in[2];
    const float* Wv    = (const float*)d_in[3];
    const float* Wg    = (const float*)d_in[4];
    const float* Wo    = (const float*)d_in[5];
    const float* ln1w  = (const float*)d_in[6];
    const float* ln1b  = (const float*)d_in[7];
    const float* ln2w  = (const float*)d_in[8];
    const float* ln2b  = (const float*)d_in[9];
    const float* W1    = (const float*)d_in[10];
    const float* b1    = (const float*)d_in[11];
    const float* W2    = (const float*)d_in[12];
    const float* b2    = (const float*)d_in[13];

    char* ws = (char*)d_ws;
    size_t off = 0;
    auto alloc = [&](size_t bytes) { char* p = ws + off; off += (bytes + 255) & ~(size_t)255; return p; };

    float* sin_t = (float*)alloc(SEQ * DK * 4);
    float* cos_t = (float*)alloc(SEQ * DK * 4);
    u16* wqkvg_t = (u16*)alloc((size_t)3 * QKVGN * DMODEL * 2);
    u16* wo_t    = (u16*)alloc((size_t)3 * DMODEL * VDIM * 2);
    u16* w1_t    = (u16*)alloc((size_t)3 * FDIM * DMODEL * 2);
    u16* w2_t    = (u16*)alloc((size_t)3 * DMODEL * FDIM * 2);
    u16* qkvg    = (u16*)alloc((size_t)NROWS * QKVGN * 2);      // ff1 overlays
    u16* xln     = (u16*)alloc((size_t)NROWS * DMODEL * 2);     // also h2
    u16* vt      = (u16*)alloc((size_t)NB * NHEAD * DV * SEQ * 2);  // ogb overlays (p1-dead)
    float* yb    = (float*)alloc((size_t)NROWS * DMODEL * 4);
    float* xbuf  = (float*)alloc((size_t)NROWS * DMODEL * 4);
    u16* po      = (u16*)alloc((size_t)8 * NSLOT * 64 * 128 * 2);   // 18.9MB; pWh overlays (8MB)
    float* pden  = (float*)alloc((size_t)8 * NSLOT * 64 * 4);
    u16* ff1 = qkvg;
    u16* h2  = xln;
    u16* ogb = vt;        // overlay: vt dead after p1; ogb consumed before next layer's qkvg GEMM
    u16* pWh = po;        // bf16 split-K partials

    // merged setup: tables + weight transposes + layer-0 LN in one launch
    setup_kernel<<<4608, 256, 0, stream>>>(Wq, Wk, Wv, Wg, Wo, W1, W2,
                                           wqkvg_t, wo_t, w1_t, w2_t, sin_t, cos_t,
                                           x0, ln1w, ln1b, xln);

    const float* xres = x0;   // residual input of current layer
    for (int i = 0; i < 3; ++i) {
        const u16* wqkvgi = wqkvg_t + (size_t)i * QKVGN * DMODEL;
        const u16* woi = wo_t + (size_t)i * DMODEL * VDIM;
        const u16* w1i = w1_t + (size_t)i * FDIM * DMODEL;
        const u16* w2i = w2_t + (size_t)i * DMODEL * FDIM;

        // fused Q|K|V|G projection: rotary on q/k, v written directly to transposed vt (BN=128)
        gemm64<0,0,1,1,0,1,128><<<dim3(QKVGN/128, NROWS/64), 256, 0, stream>>>(
            xln, wqkvgi, qkvg, nullptr, sin_t, cos_t, vt, NROWS, QKVGN, DMODEL, 0);

        retention_p1<<<dim3(NSLOT * NB * NHEAD), 256, 0, stream>>>(qkvg, vt, po, pden);
        retention_p2<<<dim3((SEQ/64) * NB * NHEAD), 256, 0, stream>>>(po, pden, qkvg, ogb);

        // y = og @ Wo + xres : split-K x4 (bf16 partials), combined in lncomb
        gemm64<0,0,0,0,1,0,64><<<dim3(DMODEL/64, NROWS/64, 4), 256, 0, stream>>>(
            ogb, woi, pWh, nullptr, nullptr, nullptr, nullptr, NROWS, DMODEL, VDIM, 128);
        lncomb_kernel<4,0><<<NROWS / 4, 256, 0, stream>>>(pWh, nullptr, xres,
            ln2w + i * DMODEL, ln2b + i * DMODEL, yb, h2);

        // ff1 = gelu(h2 @ W1 + b1)
        gemm64<1,1,0,1,0,0,64><<<dim3(FDIM/64, NROWS/64), 256, 0, stream>>>(
            h2, w1i, ff1, b1 + (size_t)i * FDIM, nullptr, nullptr, nullptr, NROWS, FDIM, DMODEL, 0);

        // x_next = ff1 @ W2 + b2 + yb : split-K x4 (bf16 partials)
        gemm64<0,0,0,0,1,0,64><<<dim3(DMODEL/64, NROWS/64, 4), 256, 0, stream>>>(
            ff1, w2i, pWh, nullptr, nullptr, nullptr, nullptr, NROWS, DMODEL, FDIM, 256);

        if (i < 2) {
            lncomb_kernel<4,1><<<NROWS / 4, 256, 0, stream>>>(pWh, b2 + (size_t)i * DMODEL, yb,
                ln1w + (i + 1) * DMODEL, ln1b + (i + 1) * DMODEL, xbuf, xln);
            xres = xbuf;
        } else {
            comb4_kernel<<<NROWS / 4, 256, 0, stream>>>(pWh, b2 + (size_t)i * DMODEL, yb, (float*)d_out);
        }
    }
}

// Round 22
// 241.158 us; speedup vs baseline: 1.0408x; 1.0408x over previous
//
#include <hip/hip_runtime.h>
#include <hip/hip_bf16.h>
#include <cstddef>
#include <cmath>
#include <algorithm>

#define SEQ 2048
#define DMODEL 256
#define NHEAD 4
#define DK 64
#define VDIM 512
#define DV 128
#define NB 2
#define FDIM 1024
#define NROWS (NB*SEQ)   // 4096
#define QKVGN 1536       // 256 q + 256 k + 512 v + 512 g
#define NSLOT 144        // q64-tiles: sum over qt64 of ((qt64>>2)+1)

typedef unsigned short u16;
typedef __attribute__((ext_vector_type(8))) short short8;
typedef __attribute__((ext_vector_type(4))) short short4v;
typedef __attribute__((ext_vector_type(4))) float f32x4;

static __device__ __forceinline__ u16 f2b(float f) {
    union { float f; unsigned u; } c; c.f = f;
    unsigned r = c.u + 0x7fffu + ((c.u >> 16) & 1u);
    return (u16)(r >> 16);
}
static __device__ __forceinline__ float b2f(u16 u) {
    union { unsigned u; float f; } c; c.u = ((unsigned)u) << 16; return c.f;
}

static __device__ __forceinline__ short4v pack_bf16x4(float a0, float a1, float a2, float a3) {
    union { short4v v; unsigned u[2]; } z;
    union { __hip_bfloat162 h; unsigned u; } p0, p1;
    p0.h = __float22bfloat162_rn(make_float2(a0, a1));
    p1.h = __float22bfloat162_rn(make_float2(a2, a3));
    z.u[0] = p0.u; z.u[1] = p1.u;
    return z.v;
}

static __device__ __forceinline__ short8 pack_bf16x8(float a0, float a1, float a2, float a3,
                                                     float c0, float c1, float c2, float c3) {
    union { short8 v; unsigned u[4]; } z;
    union { __hip_bfloat162 h; unsigned u; } p;
    p.h = __float22bfloat162_rn(make_float2(a0, a1)); z.u[0] = p.u;
    p.h = __float22bfloat162_rn(make_float2(a2, a3)); z.u[1] = p.u;
    p.h = __float22bfloat162_rn(make_float2(c0, c1)); z.u[2] = p.u;
    p.h = __float22bfloat162_rn(make_float2(c2, c3)); z.u[3] = p.u;
    return z.v;
}

// async global -> LDS, 16B per lane (wave-uniform LDS base + lane*16)
#define GLOAD_LDS16(GP, LP) \
    __builtin_amdgcn_global_load_lds((const __attribute__((address_space(1))) void*)(GP), \
                                     (__attribute__((address_space(3))) void*)(LP), 16, 0, 0)

// ---------------- merged setup: sin/cos tables + all 7 weight transposes + layer-0 LN ----------------
// grid 4608 x 256: blocks 0..511 = tables; 512..3583 = wconv; 3584..4607 = LN of x0.
__global__ __launch_bounds__(256) void setup_kernel(
    const float* __restrict__ Wq, const float* __restrict__ Wk,
    const float* __restrict__ Wv, const float* __restrict__ Wg,
    const float* __restrict__ Wo, const float* __restrict__ W1,
    const float* __restrict__ W2,
    u16* __restrict__ wqkvg_t, u16* __restrict__ wo_t,
    u16* __restrict__ w1_t, u16* __restrict__ w2_t,
    float* __restrict__ sint, float* __restrict__ cost,
    const float* __restrict__ x0, const float* __restrict__ ln1w,
    const float* __restrict__ ln1b, u16* __restrict__ xln)
{
    __shared__ float tile[32][33];
    int bid = blockIdx.x;
    if (bid < 512) {                       // sin/cos tables: SEQ*DK = 131072 elems
        int idx = bid * 256 + threadIdx.x;
        int s = idx >> 6, d = idx & 63;
        int j = d >> 1;
        float a = powf(10000.f, -(float)j / 31.f);
        float arg = (float)s * a;
        sint[idx] = sinf(arg);
        cost[idx] = cosf(arg);
        return;
    }
    if (bid >= 3584) {                     // layer-0 LN: wave-per-row
        int row = (bid - 3584) * 4 + (threadIdx.x >> 6);
        int lane = threadIdx.x & 63;
        size_t base = (size_t)row * DMODEL + lane * 4;
        f32x4 v = *(const f32x4*)(x0 + base);
        float s  = v[0] + v[1] + v[2] + v[3];
        float s2 = v[0]*v[0] + v[1]*v[1] + v[2]*v[2] + v[3]*v[3];
        #pragma unroll
        for (int st = 1; st < 64; st <<= 1) { s += __shfl_xor(s, st); s2 += __shfl_xor(s2, st); }
        float mu = s * (1.f / 256.f);
        float var = s2 * (1.f / 256.f) - mu * mu;
        float rstd = rsqrtf(var + 1e-5f);
        f32x4 wv = *(const f32x4*)(ln1w + lane * 4);
        f32x4 bv = *(const f32x4*)(ln1b + lane * 4);
        f32x4 r = (v - mu) * rstd * wv + bv;
        *(short4v*)(xln + base) = pack_bf16x4(r[0], r[1], r[2], r[3]);
        return;
    }
    bid -= 512;
    const float* in; u16* out; int K, N, nx, ny;
    size_t in_ls, out_ls;
    const size_t WLQ = (size_t)QKVGN * DMODEL;
    if (bid < 192)       {            in = Wq; out = wqkvg_t;              K = 256;  N = 256;  nx = 8;  ny = 8;  in_ls = 256*256;          out_ls = WLQ; }
    else if (bid < 384)  { bid -= 192;  in = Wk; out = wqkvg_t + 256*256;  K = 256;  N = 256;  nx = 8;  ny = 8;  in_ls = 256*256;          out_ls = WLQ; }
    else if (bid < 768)  { bid -= 384;  in = Wv; out = wqkvg_t + 512*256;  K = 256;  N = 512;  nx = 16; ny = 8;  in_ls = (size_t)256*512;  out_ls = WLQ; }
    else if (bid < 1152) { bid -= 768;  in = Wg; out = wqkvg_t + 1024*256; K = 256;  N = 512;  nx = 16; ny = 8;  in_ls = (size_t)256*512;  out_ls = WLQ; }
    else if (bid < 1536) { bid -= 1152; in = Wo; out = wo_t;               K = 512;  N = 256;  nx = 8;  ny = 16; in_ls = (size_t)512*256;  out_ls = (size_t)512*256; }
    else if (bid < 2304) { bid -= 1536; in = W1; out = w1_t;               K = 256;  N = 1024; nx = 32; ny = 8;  in_ls = (size_t)256*1024; out_ls = (size_t)256*1024; }
    else                 { bid -= 2304; in = W2; out = w2_t;               K = 1024; N = 256;  nx = 8;  ny = 32; in_ls = (size_t)1024*256; out_ls = (size_t)1024*256; }
    int per = nx * ny;
    int z = bid / per, rem = bid % per;
    int by = rem / nx, bx = rem % nx;
    int tx = threadIdx.x & 31, ty = threadIdx.x >> 5;
    const float* inz = in + (size_t)z * in_ls;
    u16* outz = out + (size_t)z * out_ls;
    int n0 = bx * 32, k0 = by * 32;
    #pragma unroll
    for (int r = 0; r < 4; ++r) {
        int kr = ty + r * 8;
        tile[kr][tx] = inz[(size_t)(k0 + kr) * N + n0 + tx];
    }
    __syncthreads();
    #pragma unroll
    for (int r = 0; r < 4; ++r) {
        int nr = ty + r * 8;
        outz[(size_t)(n0 + nr) * K + k0 + tx] = f2b(tile[tx][nr]);
    }
}

// -------- combine NPART bf16 split-K partials (+opt bias) + residual -> yout, then LN -> bf16 --------
template<int NPART, int HASBIAS>
__global__ __launch_bounds__(256) void lncomb_kernel(const u16* __restrict__ pW,
                                                     const float* __restrict__ bias,
                                                     const float* __restrict__ res,
                                                     const float* __restrict__ w,
                                                     const float* __restrict__ b,
                                                     float* __restrict__ yout,
                                                     u16* __restrict__ o)
{
    int row = blockIdx.x * 4 + (threadIdx.x >> 6);
    int lane = threadIdx.x & 63;
    size_t base = (size_t)row * DMODEL + lane * 4;
    const size_t PS = (size_t)NROWS * DMODEL;
    f32x4 v = *(const f32x4*)(res + base);
    #pragma unroll
    for (int k = 0; k < NPART; ++k) {
        short4v sv = *(const short4v*)(pW + base + k * PS);
        v[0] += b2f((u16)sv[0]); v[1] += b2f((u16)sv[1]);
        v[2] += b2f((u16)sv[2]); v[3] += b2f((u16)sv[3]);
    }
    if (HASBIAS) v += *(const f32x4*)(bias + lane * 4);
    *(f32x4*)(yout + base) = v;
    float s  = v[0] + v[1] + v[2] + v[3];
    float s2 = v[0]*v[0] + v[1]*v[1] + v[2]*v[2] + v[3]*v[3];
    #pragma unroll
    for (int st = 1; st < 64; st <<= 1) { s += __shfl_xor(s, st); s2 += __shfl_xor(s2, st); }
    float mu = s * (1.f / 256.f);
    float var = s2 * (1.f / 256.f) - mu * mu;
    float rstd = rsqrtf(var + 1e-5f);
    f32x4 wv = *(const f32x4*)(w + lane * 4);
    f32x4 bv = *(const f32x4*)(b + lane * 4);
    f32x4 r = (v - mu) * rstd * wv + bv;
    *(short4v*)(o + base) = pack_bf16x4(r[0], r[1], r[2], r[3]);
}

// ---- final: combine 4 bf16 W2 partials + bias + residual -> d_out (fp32), wave-per-row ----
__global__ __launch_bounds__(256) void comb4_kernel(const u16* __restrict__ pW,
                                                    const float* __restrict__ bias,
                                                    const float* __restrict__ yb,
                                                    float* __restrict__ out)
{
    int row = blockIdx.x * 4 + (threadIdx.x >> 6);
    int lane = threadIdx.x & 63;
    size_t base = (size_t)row * DMODEL + lane * 4;
    const size_t PS = (size_t)NROWS * DMODEL;
    f32x4 v = *(const f32x4*)(yb + base);
    v += *(const f32x4*)(bias + lane * 4);
    #pragma unroll
    for (int k = 0; k < 4; ++k) {
        short4v sv = *(const short4v*)(pW + base + k * PS);
        v[0] += b2f((u16)sv[0]); v[1] += b2f((u16)sv[1]);
        v[2] += b2f((u16)sv[2]); v[3] += b2f((u16)sv[3]);
    }
    *(f32x4*)(out + base) = v;
}

// ------------- 64x64 bf16 MFMA GEMM, BK=64, gload_lds staging (round-12/17/20 proven) -------------
// 4 waves (2x2), each 32x32 (2x2 frags). Both-sides XOR swizzle (8-col8).
// VT: v-cols (512..1023) written directly to transposed interleaved vt layout.
template<int BIAS, int GELU, int ROT, int OUTBF, int SPLIT, int VT>
__global__ __launch_bounds__(256) void gemm64(const u16* __restrict__ A,
                                              const u16* __restrict__ Bt,
                                              void* __restrict__ Cout,
                                              const float* __restrict__ bias,
                                              const float* __restrict__ sint,
                                              const float* __restrict__ cost,
                                              u16* __restrict__ vtout,
                                              int M, int N, int K, int kslice)
{
    __shared__ __align__(16) u16 As[64 * 64];   // [row][col8*8], col8 swizzled
    __shared__ __align__(16) u16 Bs[64 * 64];
    int bx = blockIdx.x, by = blockIdx.y;
    int tid = threadIdx.x;
    int wave = tid >> 6, lane = tid & 63;
    int wm = wave & 1, wn = wave >> 1;
    int l15 = lane & 15, lg = lane >> 4;
    int kb0 = SPLIT ? blockIdx.z * kslice : 0;
    int kcnt = SPLIT ? kslice : K;

    int L0 = wave * 64 + lane;
    int r0 = L0 >> 3, c0g = (L0 & 7) ^ ((r0 >> 1) & 7);
    int L1 = 256 + wave * 64 + lane;
    int r1 = L1 >> 3, c1g = (L1 & 7) ^ ((r1 >> 1) & 7);
    const u16* Ag0 = A + (size_t)(by * 64 + r0) * K + kb0 + c0g * 8;
    const u16* Ag1 = A + (size_t)(by * 64 + r1) * K + kb0 + c1g * 8;
    const u16* Bg0 = Bt + (size_t)(bx * 64 + r0) * K + kb0 + c0g * 8;
    const u16* Bg1 = Bt + (size_t)(bx * 64 + r1) * K + kb0 + c1g * 8;
    u16* Asw0 = &As[wave * 512];
    u16* Asw1 = &As[2048 + wave * 512];
    u16* Bsw0 = &Bs[wave * 512];
    u16* Bsw1 = &Bs[2048 + wave * 512];

    f32x4 acc[2][2] = {};
    for (int k0 = 0; k0 < kcnt; k0 += 64) {
        GLOAD_LDS16(Ag0 + k0, Asw0);
        GLOAD_LDS16(Ag1 + k0, Asw1);
        GLOAD_LDS16(Bg0 + k0, Bsw0);
        GLOAD_LDS16(Bg1 + k0, Bsw1);
        __syncthreads();               // drains vmcnt -> staged data visible
        #pragma unroll
        for (int kk = 0; kk < 2; ++kk) {
            short8 af[2], bf[2];
            #pragma unroll
            for (int i = 0; i < 2; ++i) {
                int ra = wm * 32 + i * 16 + l15;
                int rb = wn * 32 + i * 16 + l15;
                af[i] = *(const short8*)&As[ra * 64 + ((kk * 4 + lg) ^ ((ra >> 1) & 7)) * 8];
                bf[i] = *(const short8*)&Bs[rb * 64 + ((kk * 4 + lg) ^ ((rb >> 1) & 7)) * 8];
            }
            #pragma unroll
            for (int mi = 0; mi < 2; ++mi)
                #pragma unroll
                for (int ni = 0; ni < 2; ++ni)
                    acc[mi][ni] = __builtin_amdgcn_mfma_f32_16x16x32_bf16(af[mi], bf[ni], acc[mi][ni], 0, 0, 0);
        }
        __syncthreads();               // protect LDS reuse
    }

    float* Cf = (float*)Cout;
    u16* Ch = (u16*)Cout;
    u16* Chs = (u16*)Cout;   // bf16 split partials
    #pragma unroll
    for (int mi = 0; mi < 2; ++mi)
        #pragma unroll
        for (int ni = 0; ni < 2; ++ni) {
            int colb = bx * 64 + wn * 32 + ni * 16;   // wave-uniform base of this 16-col group
            if (VT && colb >= 512 && colb < 1024) {
                int col = colb + l15;
                int z = ((by >> 5) << 2) + ((col - 512) >> 7);   // b*4 + h
                int dv = (col - 512) & 127;
                int s0b = (by * 64 + wm * 32) & (SEQ - 1);
                short4v pk = pack_bf16x4(acc[mi][ni][0], acc[mi][ni][1], acc[mi][ni][2], acc[mi][ni][3]);
                *(short4v*)(vtout + (size_t)(z * DV + dv) * SEQ + s0b + lg * 8 + mi * 4) = pk;
            } else {
                #pragma unroll
                for (int r = 0; r < 4; ++r) {
                    int row = by * 64 + wm * 32 + mi * 16 + lg * 4 + r;
                    int col = colb + l15;
                    float v = acc[mi][ni][r];
                    if (ROT) {
                        float pv = __shfl_xor(v, 1);   // partner (col^1), group-uniform branch
                        if (col < 512) {
                            int s = row & (SEQ - 1);
                            int dk = col & 63;
                            float c = cost[(s << 6) + dk], sn = sint[(s << 6) + dk];
                            float rv = (col & 1) ? (v * c + pv * sn) : (v * c - pv * sn);
                            v = (col < 256) ? rv : rv * 0.125f;   // k gets DK^-0.5
                        }
                    }
                    if (BIAS) v += bias[col];
                    if (GELU) v = 0.5f * v * (1.f + erff(v * 0.70710678118654752f));
                    if (SPLIT)      Chs[(size_t)blockIdx.z * M * N + (size_t)row * N + col] = f2b(v);
                    else if (OUTBF) Ch[(size_t)row * N + col] = f2b(v);
                    else            Cf[(size_t)row * N + col] = v;
                }
            }
        }
}

// ---------------- retention pass 1 (swapped-QK, LDS-staged 2-phase, 64 q-rows/block) ----
// 1D grid 1152: bh = bid&7 (XCD pin), f = bid>>3 = slot decoding (qt64, chunk of 8 kv-tiles).
// 4 waves: wq in 0..3, each 16 q-rows x all 128 dv.
// PV uses full K=32 MFMA: the interleaved V layout (p = lg*8 + tt*4 + r <-> t = tt*16+lg*4+r)
// IS the 16x16x32 B-frag k-ordering when A is packed as [a0..a3, c0..c3].
__global__ __launch_bounds__(256) void retention_p1(
    const u16* __restrict__ qkvg, const u16* __restrict__ vt,
    u16* __restrict__ po, float* __restrict__ pden)
{
    __shared__ __align__(16) u16 Klds[2][2048];   // [8 seg][32 row][8 halves]
    __shared__ __align__(16) u16 Vlds[2][4096];   // [128 dv][32 halves interleaved]

    int bid = blockIdx.x;
    int bh = bid & 7;
    int f = bid >> 3;
    int a = 0, base = 0;
    while (f >= base + 4 * (a + 1)) { base += 4 * (a + 1); ++a; }   // tiers of 4 qt64s
    int segs = f - base;
    int qt64 = 4 * a + segs / (a + 1);
    int ch = segs % (a + 1);
    int b = bh >> 2, h = bh & 3;
    int slot = bh * NSLOT + f;

    int tid = threadIdx.x;
    int wave = tid >> 6, lane = tid & 63;
    int wq = wave;
    int l15 = lane & 15, lg = lane >> 4;

    float rgeo = 1.f - exp2f(-5.f - (float)h);
    float dec2 = log2f(rgeo);
    float step = exp2f(dec2 * -32.f);       // r^-32

    const u16* qbase  = qkvg + (size_t)b * SEQ * QKVGN + h * 64;
    const u16* kbase  = qbase + 256;
    const u16* vtg    = vt + (size_t)bh * DV * SEQ;

    int q0w = qt64 * 64 + wq * 16;
    short8 qf0 = *(const short8*)(qbase + (size_t)(q0w + l15) * QKVGN + lg * 8);
    short8 qf1 = *(const short8*)(qbase + (size_t)(q0w + l15) * QKVGN + 32 + lg * 8);

    int tb = ch * 8;                          // first kv-tile of this chunk
    int t_last = (ch == a) ? (2 * qt64 + 1) : (tb + 7);
    int hasdiag = (ch == a);

    float rinv  = exp2f(-dec2);               // r^-1
    float r16   = exp2f(dec2 * -16.f);        // r^-16
    float et00 = exp2f(dec2 * -(float)(tb * 32 + lg * 4));
    float et01 = et00 * rinv;
    float et02 = et01 * rinv;
    float et03 = et02 * rinv;
    float et10 = et00 * r16, et11 = et01 * r16, et12 = et02 * r16, et13 = et03 * r16;

    f32x4 oacc0 = {0.f,0.f,0.f,0.f}, oacc1 = {0.f,0.f,0.f,0.f};
    f32x4 oacc2 = {0.f,0.f,0.f,0.f}, oacc3 = {0.f,0.f,0.f,0.f};
    f32x4 oacc4 = {0.f,0.f,0.f,0.f}, oacc5 = {0.f,0.f,0.f,0.f};
    f32x4 oacc6 = {0.f,0.f,0.f,0.f}, oacc7 = {0.f,0.f,0.f,0.f};
    float den_l = 0.f;

#define STAGE(BUF, TI) do { \
    int t0_ = (TI) * 32; \
    _Pragma("unroll") \
    for (int ii = 0; ii < 3; ++ii) { \
        int inst_ = wave * 3 + ii; \
        if (inst_ < 4) { \
            const u16* g_ = kbase + (size_t)(t0_ + (lane & 31)) * QKVGN + (2 * inst_ + (lane >> 5)) * 8; \
            GLOAD_LDS16(g_, &Klds[BUF][inst_ * 512]); \
        } else { \
            int j_ = inst_ - 4; \
            const u16* g_ = vtg + (size_t)(j_ * 16 + (lane >> 2)) * SEQ + t0_ + (lane & 3) * 8; \
            GLOAD_LDS16(g_, &Vlds[BUF][j_ * 512]); \
        } \
    } \
} while (0)

#define BODY(BUF, T0, DIAG) do { \
    const u16* kb_ = &Klds[BUF][0]; \
    const u16* vb_ = &Vlds[BUF][0]; \
    short8 k00 = *(const short8*)(kb_ + (lg    ) * 256 + l15 * 8); \
    short8 k01 = *(const short8*)(kb_ + (4 + lg) * 256 + l15 * 8); \
    short8 k10 = *(const short8*)(kb_ + (lg    ) * 256 + (16 + l15) * 8); \
    short8 k11 = *(const short8*)(kb_ + (4 + lg) * 256 + (16 + l15) * 8); \
    short8 V0 = *(const short8*)(vb_ + (      l15) * 32 + lg * 8); \
    short8 V1 = *(const short8*)(vb_ + (16 +  l15) * 32 + lg * 8); \
    short8 V2 = *(const short8*)(vb_ + (32 +  l15) * 32 + lg * 8); \
    short8 V3 = *(const short8*)(vb_ + (48 +  l15) * 32 + lg * 8); \
    short8 V4 = *(const short8*)(vb_ + (64 +  l15) * 32 + lg * 8); \
    short8 V5 = *(const short8*)(vb_ + (80 +  l15) * 32 + lg * 8); \
    short8 V6 = *(const short8*)(vb_ + (96 +  l15) * 32 + lg * 8); \
    short8 V7 = *(const short8*)(vb_ + (112 + l15) * 32 + lg * 8); \
    f32x4 s0 = {0.f,0.f,0.f,0.f}, s1 = {0.f,0.f,0.f,0.f}; \
    s0 = __builtin_amdgcn_mfma_f32_16x16x32_bf16(k00, qf0, s0, 0, 0, 0); \
    s0 = __builtin_amdgcn_mfma_f32_16x16x32_bf16(k01, qf1, s0, 0, 0, 0); \
    s1 = __builtin_amdgcn_mfma_f32_16x16x32_bf16(k10, qf0, s1, 0, 0, 0); \
    s1 = __builtin_amdgcn_mfma_f32_16x16x32_bf16(k11, qf1, s1, 0, 0, 0); \
    float a0 = s0[0] * et00, a1 = s0[1] * et01, a2 = s0[2] * et02, a3 = s0[3] * et03; \
    float c0 = s1[0] * et10, c1 = s1[1] * et11, c2 = s1[2] * et12, c3 = s1[3] * et13; \
    if (DIAG) { \
        int qr_ = q0w + l15; \
        int tg_ = (T0) + lg * 4; \
        a0 = (tg_ +  0 <= qr_) ? a0 : 0.f;  a1 = (tg_ +  1 <= qr_) ? a1 : 0.f; \
        a2 = (tg_ +  2 <= qr_) ? a2 : 0.f;  a3 = (tg_ +  3 <= qr_) ? a3 : 0.f; \
        c0 = (tg_ + 16 <= qr_) ? c0 : 0.f;  c1 = (tg_ + 17 <= qr_) ? c1 : 0.f; \
        c2 = (tg_ + 18 <= qr_) ? c2 : 0.f;  c3 = (tg_ + 19 <= qr_) ? c3 : 0.f; \
    } \
    den_l += fabsf(a0) + fabsf(a1) + fabsf(a2) + fabsf(a3) \
           + fabsf(c0) + fabsf(c1) + fabsf(c2) + fabsf(c3); \
    short8 pa = pack_bf16x8(a0, a1, a2, a3, c0, c1, c2, c3); \
    oacc0 = __builtin_amdgcn_mfma_f32_16x16x32_bf16(pa, V0, oacc0, 0, 0, 0); \
    oacc1 = __builtin_amdgcn_mfma_f32_16x16x32_bf16(pa, V1, oacc1, 0, 0, 0); \
    oacc2 = __builtin_amdgcn_mfma_f32_16x16x32_bf16(pa, V2, oacc2, 0, 0, 0); \
    oacc3 = __builtin_amdgcn_mfma_f32_16x16x32_bf16(pa, V3, oacc3, 0, 0, 0); \
    oacc4 = __builtin_amdgcn_mfma_f32_16x16x32_bf16(pa, V4, oacc4, 0, 0, 0); \
    oacc5 = __builtin_amdgcn_mfma_f32_16x16x32_bf16(pa, V5, oacc5, 0, 0, 0); \
    oacc6 = __builtin_amdgcn_mfma_f32_16x16x32_bf16(pa, V6, oacc6, 0, 0, 0); \
    oacc7 = __builtin_amdgcn_mfma_f32_16x16x32_bf16(pa, V7, oacc7, 0, 0, 0); \
    et00 *= step; et01 *= step; et02 *= step; et03 *= step; \
    et10 *= step; et11 *= step; et12 *= step; et13 *= step; \
} while (0)

    int ti = tb;
    STAGE(0, tb);
    __syncthreads();
    for (; ti + 2 <= t_last; ti += 2) {
        STAGE(1, ti + 1);
        BODY(0, ti * 32, 0);
        __syncthreads();
        STAGE(0, ti + 2);
        BODY(1, (ti + 1) * 32, 0);
        __syncthreads();
    }
    if (ti < t_last) {          // two tiles remain (chunk lengths are always even)
        STAGE(1, ti + 1);
        BODY(0, ti * 32, hasdiag);     // with 64-row q-blocks the diagonal spans 2 tiles
        __syncthreads();
        BODY(1, (ti + 1) * 32, hasdiag);
    } else {                    // safety: single tile
        BODY(0, ti * 32, hasdiag);
    }
#undef STAGE
#undef BODY

    den_l += __shfl_xor(den_l, 16);
    den_l += __shfl_xor(den_l, 32);
    if (lane < 16)
        pden[(size_t)slot * 64 + wq * 16 + l15] = den_l;

    u16* pobase = po + (size_t)slot * (64 * 128) + (wq * 16 + lg * 4) * 128 + l15;
    #pragma unroll
    for (int r = 0; r < 4; ++r) {
        pobase[r * 128 +   0] = f2b(oacc0[r]);
        pobase[r * 128 +  16] = f2b(oacc1[r]);
        pobase[r * 128 +  32] = f2b(oacc2[r]);
        pobase[r * 128 +  48] = f2b(oacc3[r]);
        pobase[r * 128 +  64] = f2b(oacc4[r]);
        pobase[r * 128 +  80] = f2b(oacc5[r]);
        pobase[r * 128 +  96] = f2b(oacc6[r]);
        pobase[r * 128 + 112] = f2b(oacc7[r]);
    }
}

// ---------------- retention pass 2: reduce chunks, r^q scaling, clip, RMS, swish gate ----
// 1D grid 256: bh = bid&7, qt64 = bid>>3. 64 rows/block, 32 cols/thread.
__global__ __launch_bounds__(256) void retention_p2(
    const u16* __restrict__ po, const float* __restrict__ pden,
    const u16* __restrict__ qkvg, u16* __restrict__ og)
{
    int bid = blockIdx.x;
    int bh = bid & 7;
    int qt64 = bid >> 3;
    int b = bh >> 2, h = bh & 3;
    int aa = qt64 >> 2, rr = qt64 & 3;
    int sbase = bh * NSLOT + qt64 + 2 * aa * (aa - 1) + rr * aa;
    int nch = aa + 1;
    int t = threadIdx.x;
    int row = t >> 2, c0 = (t & 3) * 32;
    int q = qt64 * 64 + row;

    float den = 0.f;
    for (int k = 0; k < nch; ++k) den += pden[(size_t)(sbase + k) * 64 + row];
    float acc[32];
    #pragma unroll
    for (int j = 0; j < 32; ++j) acc[j] = 0.f;
    for (int k = 0; k < nch; ++k) {
        const u16* p = po + (size_t)(sbase + k) * (64 * 128) + row * 128 + c0;
        #pragma unroll
        for (int j = 0; j < 32; ++j) acc[j] += b2f(p[j]);
    }
    float rgeo = 1.f - exp2f(-5.f - (float)h);
    float dec2 = log2f(rgeo);
    float rp1 = exp2f(dec2 * (float)(q + 1));
    float cs = (1.f - rp1) / (1.f - rgeo);
    float invs = rsqrtf(cs);
    float eqv = exp2f(dec2 * (float)q);          // r^q (pass-1 deferred factor)
    float d = fmaxf(den * eqv * invs, 1.f);
    float scl = eqv * invs / d;
    float ss = 0.f;
    #pragma unroll
    for (int j = 0; j < 32; ++j) { float v = acc[j] * scl; acc[j] = v; ss += v * v; }
    ss += __shfl_xor(ss, 1); ss += __shfl_xor(ss, 2);
    float rms = rsqrtf(ss * (1.f / DV) + 1e-6f);

    const u16* gbase = qkvg + ((size_t)(b * SEQ + q)) * QKVGN + 1024 + h * DV + c0;
    u16* obase = og + ((size_t)(b * SEQ + q)) * VDIM + h * DV + c0;
    #pragma unroll
    for (int j = 0; j < 32; ++j) {
        float gv = b2f(gbase[j]);
        float sig = 1.f / (1.f + __expf(-gv));
        obase[j] = f2b(gv * sig * acc[j] * rms);
    }
}

extern "C" void kernel_launch(void* const* d_in, const int* in_sizes, int n_in,
                              void* d_out, int out_size, void* d_ws, size_t ws_size,
                              hipStream_t stream)
{
    const float* x0    = (const float*)d_in[0];
    const float* Wq    = (const float*)d_in[1];
    const float* Wk    = (const float*)d_in[2];
    const float* Wv    = (const float*)d_in[3];
    const float* Wg    = (const float*)d_in[4];
    const float* Wo    = (const float*)d_in[5];
    const float* ln1w  = (const float*)d_in[6];
    const float* ln1b  = (const float*)d_in[7];
    const float* ln2w  = (const float*)d_in[8];
    const float* ln2b  = (const float*)d_in[9];
    const float* W1    = (const float*)d_in[10];
    const float* b1    = (const float*)d_in[11];
    const float* W2    = (const float*)d_in[12];
    const float* b2    = (const float*)d_in[13];

    char* ws = (char*)d_ws;
    size_t off = 0;
    auto alloc = [&](size_t bytes) { char* p = ws + off; off += (bytes + 255) & ~(size_t)255; return p; };

    float* sin_t = (float*)alloc(SEQ * DK * 4);
    float* cos_t = (float*)alloc(SEQ * DK * 4);
    u16* wqkvg_t = (u16*)alloc((size_t)3 * QKVGN * DMODEL * 2);
    u16* wo_t    = (u16*)alloc((size_t)3 * DMODEL * VDIM * 2);
    u16* w1_t    = (u16*)alloc((size_t)3 * FDIM * DMODEL * 2);
    u16* w2_t    = (u16*)alloc((size_t)3 * DMODEL * FDIM * 2);
    u16* qkvg    = (u16*)alloc((size_t)NROWS * QKVGN * 2);      // ff1 overlays
    u16* xln     = (u16*)alloc((size_t)NROWS * DMODEL * 2);     // also h2
    u16* vt      = (u16*)alloc((size_t)NB * NHEAD * DV * SEQ * 2);  // ogb overlays (p1-dead)
    float* yb    = (float*)alloc((size_t)NROWS * DMODEL * 4);
    float* xbuf  = (float*)alloc((size_t)NROWS * DMODEL * 4);
    u16* po      = (u16*)alloc((size_t)8 * NSLOT * 64 * 128 * 2);   // 18.9MB; pWh overlays (8MB)
    float* pden  = (float*)alloc((size_t)8 * NSLOT * 64 * 4);
    u16* ff1 = qkvg;
    u16* h2  = xln;
    u16* ogb = vt;        // overlay: vt dead after p1; ogb consumed before next layer's qkvg GEMM
    u16* pWh = po;        // bf16 split-K partials

    // merged setup: tables + weight transposes + layer-0 LN in one launch
    setup_kernel<<<4608, 256, 0, stream>>>(Wq, Wk, Wv, Wg, Wo, W1, W2,
                                           wqkvg_t, wo_t, w1_t, w2_t, sin_t, cos_t,
                                           x0, ln1w, ln1b, xln);

    const float* xres = x0;   // residual input of current layer
    for (int i = 0; i < 3; ++i) {
        const u16* wqkvgi = wqkvg_t + (size_t)i * QKVGN * DMODEL;
        const u16* woi = wo_t + (size_t)i * DMODEL * VDIM;
        const u16* w1i = w1_t + (size_t)i * FDIM * DMODEL;
        const u16* w2i = w2_t + (size_t)i * DMODEL * FDIM;

        // fused Q|K|V|G projection: rotary on q/k, v written directly to transposed vt
        gemm64<0,0,1,1,0,1><<<dim3(QKVGN/64, NROWS/64), 256, 0, stream>>>(
            xln, wqkvgi, qkvg, nullptr, sin_t, cos_t, vt, NROWS, QKVGN, DMODEL, 0);

        retention_p1<<<dim3(NSLOT * NB * NHEAD), 256, 0, stream>>>(qkvg, vt, po, pden);
        retention_p2<<<dim3((SEQ/64) * NB * NHEAD), 256, 0, stream>>>(po, pden, qkvg, ogb);

        // y = og @ Wo + xres : split-K x4 (bf16 partials), combined in lncomb
        gemm64<0,0,0,0,1,0><<<dim3(DMODEL/64, NROWS/64, 4), 256, 0, stream>>>(
            ogb, woi, pWh, nullptr, nullptr, nullptr, nullptr, NROWS, DMODEL, VDIM, 128);
        lncomb_kernel<4,0><<<NROWS / 4, 256, 0, stream>>>(pWh, nullptr, xres,
            ln2w + i * DMODEL, ln2b + i * DMODEL, yb, h2);

        // ff1 = gelu(h2 @ W1 + b1)
        gemm64<1,1,0,1,0,0><<<dim3(FDIM/64, NROWS/64), 256, 0, stream>>>(
            h2, w1i, ff1, b1 + (size_t)i * FDIM, nullptr, nullptr, nullptr, NROWS, FDIM, DMODEL, 0);

        // x_next = ff1 @ W2 + b2 + yb : split-K x4 (bf16 partials)
        gemm64<0,0,0,0,1,0><<<dim3(DMODEL/64, NROWS/64, 4), 256, 0, stream>>>(
            ff1, w2i, pWh, nullptr, nullptr, nullptr, nullptr, NROWS, DMODEL, FDIM, 256);

        if (i < 2) {
            lncomb_kernel<4,1><<<NROWS / 4, 256, 0, stream>>>(pWh, b2 + (size_t)i * DMODEL, yb,
                ln1w + (i + 1) * DMODEL, ln1b + (i + 1) * DMODEL, xbuf, xln);
            xres = xbuf;
        } else {
            comb4_kernel<<<NROWS / 4, 256, 0, stream>>>(pWh, b2 + (size_t)i * DMODEL, yb, (float*)d_out);
        }
    }
}